// Round 4
// baseline (71.031 us; speedup 1.0000x reference)
//
#include <hip/hip_runtime.h>
#include <hip/hip_bf16.h>

// CombinedRotaryEmbedding via MFMA.
// prep (1 wave): fold Givens chain into rotation_matrix -> M (64x64), apply
//   RoPE even/odd column permutation, split into bf16 hi/lo, store as
//   mfma_f32_16x16x32_bf16 B-fragments in d_ws.
// main: per wave, 16 head-rows of ONE token = 16x64 A tile.
//   Y = Ahi*Bhi + Alo*Bhi + Ahi*Blo (3-term bf16 split ~ fp32 accuracy).
//   Register double-buffer: tile t+1's 4 global_load_dwordx4 are issued
//   before tile t's compute, keeping 4 KB/wave in flight at all times
//   (R3 post-mortem: waves were MLP-starved, stalled in vmcnt with nothing
//   outstanding). Grid = 1024 blocks = 4 blocks/CU, one fully-resident round.

#define TILES_PER_WAVE 8
#define N_TILES 32768                   // B*S tokens
#define N_WAVES (N_TILES / TILES_PER_WAVE)
#define N_BLOCKS (N_WAVES / 4)          // 1024

typedef __attribute__((ext_vector_type(8))) short short8;
typedef __attribute__((ext_vector_type(4))) float f32x4;

__device__ __forceinline__ unsigned short f2bf(float f) {
  unsigned int u = __float_as_uint(f);
  u += 0x7fff + ((u >> 16) & 1);  // RNE
  return (unsigned short)(u >> 16);
}
__device__ __forceinline__ float bf2f(unsigned short h) {
  return __uint_as_float(((unsigned int)h) << 16);
}

__global__ __launch_bounds__(64) void prep_kernel(
    const float* __restrict__ thetas,
    const float* __restrict__ R,
    short* __restrict__ Bws) {
  const int t = threadIdx.x;  // 0..63
  float col[64];
#pragma unroll
  for (int d = 0; d < 64; ++d) col[d] = R[d * 64 + t];
#pragma unroll
  for (int k = 31; k >= 0; --k) {
    float th = thetas[k];
    float ck = cosf(th), sk = sinf(th);
    float a = col[k], b = col[k + 1];
    col[k]     = ck * a - sk * b;
    col[k + 1] = sk * a + ck * b;
  }
  __shared__ float Ml[64][64];
#pragma unroll
  for (int d = 0; d < 64; ++d) Ml[d][t] = col[d];
  __syncthreads();

  short8* Bp = (short8*)Bws;
  const int cb = t & 15, kg = t >> 4;
#pragma unroll
  for (int s = 0; s < 2; ++s) {
#pragma unroll
    for (int nt = 0; nt < 4; ++nt) {
      const int c2 = cb + 16 * nt;
      const int pc = (c2 < 32) ? (2 * c2) : (2 * (c2 - 32) + 1);
      short8 hf, lf;
#pragma unroll
      for (int e = 0; e < 8; ++e) {
        const int k = s * 32 + kg * 8 + e;
        float m = Ml[k][pc];
        unsigned short hi = f2bf(m);
        unsigned short lo = f2bf(m - bf2f(hi));
        hf[e] = (short)hi;
        lf[e] = (short)lo;
      }
      Bp[(s * 4 + nt) * 64 + t] = hf;        // hi frags: idx 0..7
      Bp[(8 + s * 4 + nt) * 64 + t] = lf;    // lo frags: idx 8..15
    }
  }
}

__global__ __launch_bounds__(256, 4) void rope_mfma(
    const float* __restrict__ x,
    const float* __restrict__ inv_freq,
    const short* __restrict__ Bws,
    float* __restrict__ out) {
  const int lane = threadIdx.x & 63;
  const int wave = (int)blockIdx.x * 4 + (int)(threadIdx.x >> 6);
  const int cb = lane & 15;   // A row within tile / D col within 16-block
  const int kg = lane >> 4;   // k-group

  const int tile0 = wave * TILES_PER_WAVE;

  // Issue first A-tile prefetch BEFORE the B-fragment loads.
  const float4* xr = (const float4*)(x + ((size_t)tile0 * 16 + cb) * 64 + kg * 8);
  float4 p0 = xr[0], p1 = xr[1], p2 = xr[8], p3 = xr[9];

  const short8* Bp = (const short8*)Bws;
  short8 bh[8], bl[8];  // idx = s*4 + nt; 16 KB table -> L2 resident
#pragma unroll
  for (int i = 0; i < 8; ++i) {
    bh[i] = Bp[i * 64 + lane];
    bl[i] = Bp[(8 + i) * 64 + lane];
  }

  const float ivf0 = inv_freq[cb];
  const float ivf1 = inv_freq[cb + 16];

#pragma unroll 1
  for (int t = 0; t < TILES_PER_WAVE; ++t) {
    const int tile = tile0 + t;                   // == token index
    const size_t rb = (size_t)tile * 16;          // first head-row of tile

    // sincos depends only on tile index — overlaps the load stall.
    const int pos = tile & 8191;
    float sv0, cv0, sv1, cv1;
    __sincosf((float)pos * ivf0, &sv0, &cv0);
    __sincosf((float)pos * ivf1, &sv1, &cv1);

    // Consume prefetched tile (compiler inserts the vmcnt wait here),
    // then immediately issue tile t+1's loads so 4 KB stays in flight.
    float4 c0 = p0, c1 = p1, c2 = p2, c3 = p3;
    if (t + 1 < TILES_PER_WAVE) {
      const float4* xn =
          (const float4*)(x + (rb + 16 + cb) * 64 + kg * 8);
      p0 = xn[0]; p1 = xn[1]; p2 = xn[8]; p3 = xn[9];
    }

    short8 ah[2], al[2];
    {
      const float* qs[2][2] = {{(float*)&c0, (float*)&c1}, {(float*)&c2, (float*)&c3}};
#pragma unroll
      for (int s = 0; s < 2; ++s) {
#pragma unroll
        for (int e = 0; e < 8; ++e) {
          float f = qs[s][e >> 2][e & 3];
          unsigned short hi = f2bf(f);
          unsigned short lo = f2bf(f - bf2f(hi));
          ah[s][e] = (short)hi;
          al[s][e] = (short)lo;
        }
      }
    }

    f32x4 acc[4];
#pragma unroll
    for (int nt = 0; nt < 4; ++nt) acc[nt] = (f32x4){0.f, 0.f, 0.f, 0.f};
#pragma unroll
    for (int s = 0; s < 2; ++s) {
#pragma unroll
      for (int nt = 0; nt < 4; ++nt) {
        acc[nt] = __builtin_amdgcn_mfma_f32_16x16x32_bf16(ah[s], bh[s * 4 + nt], acc[nt], 0, 0, 0);
        acc[nt] = __builtin_amdgcn_mfma_f32_16x16x32_bf16(al[s], bh[s * 4 + nt], acc[nt], 0, 0, 0);
        acc[nt] = __builtin_amdgcn_mfma_f32_16x16x32_bf16(ah[s], bl[s * 4 + nt], acc[nt], 0, 0, 0);
      }
    }

    float* orow = out + rb * 64;
#pragma unroll
    for (int nt = 0; nt < 4; ++nt) {
      const float cvx = (nt & 1) ? cv1 : cv0;
      const float ssv = ((nt & 1) ? sv1 : sv0) * ((nt < 2) ? -1.f : 1.f);
#pragma unroll
      for (int r = 0; r < 4; ++r) {
        float y = acc[nt][r];
        float p = acc[nt ^ 2][r];
        orow[(kg * 4 + r) * 64 + cb + 16 * nt] = fmaf(p, ssv, y * cvx);
      }
    }
  }
}

extern "C" void kernel_launch(void* const* d_in, const int* in_sizes, int n_in,
                              void* d_out, int out_size, void* d_ws, size_t ws_size,
                              hipStream_t stream) {
  const float* x        = (const float*)d_in[0];
  const float* thetas   = (const float*)d_in[1];
  const float* R        = (const float*)d_in[2];
  const float* inv_freq = (const float*)d_in[3];

  prep_kernel<<<1, 64, 0, stream>>>(thetas, R, (short*)d_ws);
  rope_mfma<<<N_BLOCKS, 256, 0, stream>>>(x, inv_freq, (const short*)d_ws, (float*)d_out);
}

// Round 5
// 58.892 us; speedup vs baseline: 1.2061x; 1.2061x over previous
//
#include <hip/hip_runtime.h>
#include <hip/hip_bf16.h>

// CombinedRotaryEmbedding via MFMA.
// prep (1 wave): fold Givens chain into rotation_matrix -> M (64x64), apply
//   RoPE even/odd column permutation, quantize to bf16, store as
//   mfma_f32_16x16x32_bf16 B-fragments (8 frags, 8 KB) in d_ws.
// main: per wave, 16 head-rows of ONE token = 16x64 A tile.
//   Y = Ahi*B + Alo*B (A split to hi/lo bf16 ~ fp32-accurate A; B plain bf16).
//   R4 post-mortem: compiler rematerialized B-fragment loads inside the tile
//   loop (VGPR_Count=64 << needed), putting 16 L2 loads on every tile's
//   critical path. Fix: 2-term split (B = 32 VGPR) + per-iteration asm pin
//   so B is genuinely loop-resident.

#define TILES_PER_WAVE 8
#define N_TILES 32768                   // B*S tokens
#define N_WAVES (N_TILES / TILES_PER_WAVE)
#define N_BLOCKS (N_WAVES / 4)          // 1024 = 4 blocks/CU exactly

typedef __attribute__((ext_vector_type(8))) short short8;
typedef __attribute__((ext_vector_type(4))) float f32x4;

__device__ __forceinline__ unsigned short f2bf_bits(float f) {
  return __bfloat16_as_ushort(__float2bfloat16(f));
}

__global__ __launch_bounds__(64) void prep_kernel(
    const float* __restrict__ thetas,
    const float* __restrict__ R,
    short* __restrict__ Bws) {
  const int t = threadIdx.x;  // 0..63
  float col[64];
#pragma unroll
  for (int d = 0; d < 64; ++d) col[d] = R[d * 64 + t];
  // M = G0 G1 ... G31 R ; Gk mixes rows k,k+1 (lane-local here).
#pragma unroll
  for (int k = 31; k >= 0; --k) {
    float th = thetas[k];
    float ck = cosf(th), sk = sinf(th);
    float a = col[k], b = col[k + 1];
    col[k]     = ck * a - sk * b;
    col[k + 1] = sk * a + ck * b;
  }
  __shared__ float Ml[64][64];
#pragma unroll
  for (int d = 0; d < 64; ++d) Ml[d][t] = col[d];
  __syncthreads();

  // B fragment for mfma_f32_16x16x32_bf16: col=lane&15, k=(lane>>4)*8+e,
  // frag index i = s*4+nt covers k in [s*32, s*32+32), cols [16*nt, 16*nt+16).
  short8* Bp = (short8*)Bws;
  const int cb = t & 15, kg = t >> 4;
#pragma unroll
  for (int s = 0; s < 2; ++s) {
#pragma unroll
    for (int nt = 0; nt < 4; ++nt) {
      const int c2 = cb + 16 * nt;
      const int pc = (c2 < 32) ? (2 * c2) : (2 * (c2 - 32) + 1);  // RoPE perm
      short8 hf;
#pragma unroll
      for (int e = 0; e < 8; ++e) {
        const int k = s * 32 + kg * 8 + e;
        hf[e] = (short)f2bf_bits(Ml[k][pc]);
      }
      Bp[(s * 4 + nt) * 64 + t] = hf;
    }
  }
}

__global__ __launch_bounds__(256, 4) void rope_mfma(
    const float* __restrict__ x,
    const float* __restrict__ inv_freq,
    const short* __restrict__ Bws,
    float* __restrict__ out) {
  const int lane = threadIdx.x & 63;
  const int wave = (int)blockIdx.x * 4 + (int)(threadIdx.x >> 6);
  const int cb = lane & 15;   // A row within tile / D col within 16-block
  const int kg = lane >> 4;   // k-group

  const int tile0 = wave * TILES_PER_WAVE;

  // First A-tile prefetch issued before the B loads.
  const float4* xr = (const float4*)(x + ((size_t)tile0 * 16 + cb) * 64 + kg * 8);
  float4 p0 = xr[0], p1 = xr[1], p2 = xr[8], p3 = xr[9];

  const short8* Bp = (const short8*)Bws;
  short8 bh[8];  // 32 VGPR, pinned resident below
#pragma unroll
  for (int i = 0; i < 8; ++i) bh[i] = Bp[i * 64 + lane];

  const float ivf0 = inv_freq[cb];
  const float ivf1 = inv_freq[cb + 16];

#pragma unroll 1
  for (int t = 0; t < TILES_PER_WAVE; ++t) {
    // Pin B fragments: forces them to live in VGPRs each iteration so the
    // compiler cannot rematerialize the global loads inside the loop.
#pragma unroll
    for (int i = 0; i < 8; ++i) asm volatile("" : "+v"(bh[i]));

    const int tile = tile0 + t;                   // == token index
    const size_t rb = (size_t)tile * 16;          // first head-row of tile

    // sincos depends only on tile index — overlaps the load stall.
    const int pos = tile & 8191;
    float sv0, cv0, sv1, cv1;
    __sincosf((float)pos * ivf0, &sv0, &cv0);
    __sincosf((float)pos * ivf1, &sv1, &cv1);

    // Consume prefetched tile, then immediately issue tile t+1's loads.
    float4 c0 = p0, c1 = p1, c2 = p2, c3 = p3;
    if (t + 1 < TILES_PER_WAVE) {
      const float4* xn = (const float4*)(x + (rb + 16 + cb) * 64 + kg * 8);
      p0 = xn[0]; p1 = xn[1]; p2 = xn[8]; p3 = xn[9];
    }

    // A hi/lo bf16 split (compiler fuses to v_cvt_pk_bf16_f32).
    short8 ah[2], al[2];
    {
      const float* qs[2][2] = {{(float*)&c0, (float*)&c1}, {(float*)&c2, (float*)&c3}};
#pragma unroll
      for (int s = 0; s < 2; ++s) {
#pragma unroll
        for (int e = 0; e < 8; ++e) {
          float f = qs[s][e >> 2][e & 3];
          __hip_bfloat16 h = __float2bfloat16(f);
          ah[s][e] = (short)__bfloat16_as_ushort(h);
          al[s][e] = (short)f2bf_bits(f - __bfloat162float(h));
        }
      }
    }

    f32x4 acc[4];
#pragma unroll
    for (int nt = 0; nt < 4; ++nt) acc[nt] = (f32x4){0.f, 0.f, 0.f, 0.f};
#pragma unroll
    for (int s = 0; s < 2; ++s) {
#pragma unroll
      for (int nt = 0; nt < 4; ++nt) {
        acc[nt] = __builtin_amdgcn_mfma_f32_16x16x32_bf16(ah[s], bh[s * 4 + nt], acc[nt], 0, 0, 0);
        acc[nt] = __builtin_amdgcn_mfma_f32_16x16x32_bf16(al[s], bh[s * 4 + nt], acc[nt], 0, 0, 0);
      }
    }

    // RoPE epilogue; D layout: col = cb + 16*nt, row = kg*4 + r.
    float* orow = out + rb * 64;
#pragma unroll
    for (int nt = 0; nt < 4; ++nt) {
      const float cvx = (nt & 1) ? cv1 : cv0;
      const float ssv = ((nt & 1) ? sv1 : sv0) * ((nt < 2) ? -1.f : 1.f);
#pragma unroll
      for (int r = 0; r < 4; ++r) {
        float y = acc[nt][r];
        float p = acc[nt ^ 2][r];
        orow[(kg * 4 + r) * 64 + cb + 16 * nt] = fmaf(p, ssv, y * cvx);
      }
    }
  }
}

extern "C" void kernel_launch(void* const* d_in, const int* in_sizes, int n_in,
                              void* d_out, int out_size, void* d_ws, size_t ws_size,
                              hipStream_t stream) {
  const float* x        = (const float*)d_in[0];
  const float* thetas   = (const float*)d_in[1];
  const float* R        = (const float*)d_in[2];
  const float* inv_freq = (const float*)d_in[3];

  prep_kernel<<<1, 64, 0, stream>>>(thetas, R, (short*)d_ws);
  rope_mfma<<<N_BLOCKS, 256, 0, stream>>>(x, inv_freq, (const short*)d_ws, (float*)d_out);
}

// Round 6
// 57.513 us; speedup vs baseline: 1.2350x; 1.0240x over previous
//
#include <hip/hip_runtime.h>
#include <hip/hip_bf16.h>

// CombinedRotaryEmbedding via MFMA.
// prep (1 wave): fold Givens chain into rotation_matrix -> M (64x64), apply
//   RoPE even/odd column permutation, quantize to bf16, store as
//   mfma_f32_16x16x32_bf16 B-fragments (8 frags, 8 KB) in d_ws.
// main: ONE token (16 head-rows = 16x64 A tile) per wave, straight-line code
//   (no tile loop). R5 post-mortem: with a loop, the compiler rematerialized
//   the 8 B-fragment loads every iteration (VGPR_Count=48) and the resulting
//   vmcnt(0) drain serialized everything at ~60us regardless of structure.
//   TPW=1 makes remat structurally impossible and maximizes TLP
//   (8192 blocks -> ~32 waves/CU demanded).
//   Y = Ahi*B + Alo*B (2-term bf16 split, absmax 0.031 vs 0.118 threshold).
//   Output: acc -> XOR-swizzled per-wave LDS tile (conflict-free) -> 4 fully
//   contiguous 1KB global_store_dwordx4 (was 16 scattered store_dword).

#define N_TILES 32768                   // B*S tokens
#define N_BLOCKS (N_TILES / 4)          // 8192, one token per wave

typedef __attribute__((ext_vector_type(8))) short short8;
typedef __attribute__((ext_vector_type(4))) float f32x4;

__device__ __forceinline__ unsigned short f2bf_bits(float f) {
  return __bfloat16_as_ushort(__float2bfloat16(f));
}

__global__ __launch_bounds__(64) void prep_kernel(
    const float* __restrict__ thetas,
    const float* __restrict__ R,
    short* __restrict__ Bws) {
  const int t = threadIdx.x;  // 0..63
  float col[64];
#pragma unroll
  for (int d = 0; d < 64; ++d) col[d] = R[d * 64 + t];
  // M = G0 G1 ... G31 R ; Gk mixes rows k,k+1 (lane-local here).
#pragma unroll
  for (int k = 31; k >= 0; --k) {
    float th = thetas[k];
    float ck = cosf(th), sk = sinf(th);
    float a = col[k], b = col[k + 1];
    col[k]     = ck * a - sk * b;
    col[k + 1] = sk * a + ck * b;
  }
  __shared__ float Ml[64][64];
#pragma unroll
  for (int d = 0; d < 64; ++d) Ml[d][t] = col[d];
  __syncthreads();

  // B fragment for mfma_f32_16x16x32_bf16: col=lane&15, k=(lane>>4)*8+e.
  short8* Bp = (short8*)Bws;
  const int cb = t & 15, kg = t >> 4;
#pragma unroll
  for (int s = 0; s < 2; ++s) {
#pragma unroll
    for (int nt = 0; nt < 4; ++nt) {
      const int c2 = cb + 16 * nt;
      const int pc = (c2 < 32) ? (2 * c2) : (2 * (c2 - 32) + 1);  // RoPE perm
      short8 hf;
#pragma unroll
      for (int e = 0; e < 8; ++e) {
        const int k = s * 32 + kg * 8 + e;
        hf[e] = (short)f2bf_bits(Ml[k][pc]);
      }
      Bp[(s * 4 + nt) * 64 + t] = hf;
    }
  }
}

__global__ void rope_mfma(
    const float* __restrict__ x,
    const float* __restrict__ inv_freq,
    const short* __restrict__ Bws,
    float* __restrict__ out) {
  const int lane = threadIdx.x & 63;
  const int wid = threadIdx.x >> 6;
  const int cb = lane & 15;   // A row within tile / D col within 16-block
  const int kg = lane >> 4;   // k-group

  const int tile = (int)blockIdx.x * 4 + wid;   // token index
  const size_t rb = (size_t)tile * 16;          // first head-row

  // Issue all global loads up front: 4 x-loads + 8 B-fragment loads.
  const float4* xr = (const float4*)(x + (rb + cb) * 64 + kg * 8);
  float4 c0 = xr[0], c1 = xr[1], c2 = xr[8], c3 = xr[9];

  const short8* Bp = (const short8*)Bws;
  short8 bh[8];
#pragma unroll
  for (int i = 0; i < 8; ++i) bh[i] = Bp[i * 64 + lane];

  // sincos in the load shadow; one position per tile.
  const int pos = tile & 8191;
  float sv0, cv0, sv1, cv1;
  __sincosf((float)pos * inv_freq[cb], &sv0, &cv0);
  __sincosf((float)pos * inv_freq[cb + 16], &sv1, &cv1);

  // A hi/lo bf16 split.
  short8 ah[2], al[2];
  {
    const float* qs[2][2] = {{(float*)&c0, (float*)&c1}, {(float*)&c2, (float*)&c3}};
#pragma unroll
    for (int s = 0; s < 2; ++s) {
#pragma unroll
      for (int e = 0; e < 8; ++e) {
        float f = qs[s][e >> 2][e & 3];
        __hip_bfloat16 h = __float2bfloat16(f);
        ah[s][e] = (short)__bfloat16_as_ushort(h);
        al[s][e] = (short)f2bf_bits(f - __bfloat162float(h));
      }
    }
  }

  f32x4 acc[4];
#pragma unroll
  for (int nt = 0; nt < 4; ++nt) acc[nt] = (f32x4){0.f, 0.f, 0.f, 0.f};
#pragma unroll
  for (int s = 0; s < 2; ++s) {
#pragma unroll
    for (int nt = 0; nt < 4; ++nt) {
      acc[nt] = __builtin_amdgcn_mfma_f32_16x16x32_bf16(ah[s], bh[s * 4 + nt], acc[nt], 0, 0, 0);
      acc[nt] = __builtin_amdgcn_mfma_f32_16x16x32_bf16(al[s], bh[s * 4 + nt], acc[nt], 0, 0, 0);
    }
  }

  // RoPE combine + staged transpose through per-wave LDS (4 KB each).
  // LDS layout: 16 rows x 16 chunks of 16B; chunk XOR-swizzled by row so both
  // the scattered f32 writes and the contiguous 16B reads are conflict-free
  // (2-way max, free on CDNA4).
  __shared__ float stage[4][16 * 64];
  float* st = stage[wid];
#pragma unroll
  for (int nt = 0; nt < 4; ++nt) {
    const float cvx = (nt & 1) ? cv1 : cv0;
    const float ssv = ((nt & 1) ? sv1 : sv0) * ((nt < 2) ? -1.f : 1.f);
    const int chunk = (cb >> 2) + 4 * nt;
    const int c1i = cb & 3;
#pragma unroll
    for (int r = 0; r < 4; ++r) {
      const int lrow = kg * 4 + r;
      float y = acc[nt][r];
      float p = acc[nt ^ 2][r];
      st[lrow * 64 + ((chunk ^ lrow) << 2) + c1i] = fmaf(p, ssv, y * cvx);
    }
  }
  // Per-wave staging only: no cross-wave sharing, lgkmcnt ordering suffices.
  asm volatile("s_waitcnt lgkmcnt(0)");
#pragma unroll
  for (int i = 0; i < 4; ++i) {
    const int g = i * 4 + kg;                      // output row within tile
    const float4 v = *(const float4*)&st[g * 64 + ((cb ^ g) << 2)];
    ((float4*)(out + (rb + g) * 64))[cb] = v;      // 1 KB contiguous per instr
  }
}

extern "C" void kernel_launch(void* const* d_in, const int* in_sizes, int n_in,
                              void* d_out, int out_size, void* d_ws, size_t ws_size,
                              hipStream_t stream) {
  const float* x        = (const float*)d_in[0];
  const float* thetas   = (const float*)d_in[1];
  const float* R        = (const float*)d_in[2];
  const float* inv_freq = (const float*)d_in[3];

  prep_kernel<<<1, 64, 0, stream>>>(thetas, R, (short*)d_ws);
  rope_mfma<<<N_BLOCKS, 256, 0, stream>>>(x, inv_freq, (const short*)d_ws, (float*)d_out);
}

// Round 8
// 54.210 us; speedup vs baseline: 1.3103x; 1.0609x over previous
//
#include <hip/hip_runtime.h>
#include <hip/hip_bf16.h>

// CombinedRotaryEmbedding via MFMA.
// prep (1 wave): fold Givens chain into rotation_matrix -> M (64x64), apply
//   RoPE even/odd column permutation, quantize to bf16, store as
//   mfma_f32_16x16x32_bf16 B-fragments (8 KB) in d_ws.
// main: ONE token (16 rows x 64 cols f32 = 4 KB) per wave, straight-line.
//   R6 post-mortem: all structures land ~57-61us at 4.7 TB/s while pure
//   streaming writes hit 7 TB/s on the same capture. The never-changed
//   invariant was the gapped x-load pattern (16B segments, 32B gaps).
//   Now: 4 fully-contiguous 1KB global_load_dwordx4 -> XOR-swizzled per-wave
//   LDS stage -> ds_read_b128 A-fragments. Output: epilogue -> same LDS
//   buffer -> 4 contiguous 1KB nontemporal dwordx4 stores. No barriers
//   (per-wave staging; DS ops are in-order within a wave).
// R7: compile fix — __builtin_nontemporal_store needs ext_vector_type,
//   not HIP_vector_type<float,4>.

#define N_TILES 32768                   // B*S tokens
#define N_BLOCKS (N_TILES / 4)          // 8192 blocks, 1 token per wave

typedef __attribute__((ext_vector_type(8))) short short8;
typedef __attribute__((ext_vector_type(4))) float f32x4;

__device__ __forceinline__ unsigned short f2bf_bits(float f) {
  return __bfloat16_as_ushort(__float2bfloat16(f));
}

__global__ __launch_bounds__(64) void prep_kernel(
    const float* __restrict__ thetas,
    const float* __restrict__ R,
    short* __restrict__ Bws) {
  const int t = threadIdx.x;  // 0..63
  float col[64];
#pragma unroll
  for (int d = 0; d < 64; ++d) col[d] = R[d * 64 + t];
  // M = G0 G1 ... G31 R ; Gk mixes rows k,k+1 (lane-local here).
#pragma unroll
  for (int k = 31; k >= 0; --k) {
    float th = thetas[k];
    float ck = cosf(th), sk = sinf(th);
    float a = col[k], b = col[k + 1];
    col[k]     = ck * a - sk * b;
    col[k + 1] = sk * a + ck * b;
  }
  __shared__ float Ml[64][64];
#pragma unroll
  for (int d = 0; d < 64; ++d) Ml[d][t] = col[d];
  __syncthreads();

  // B fragment for mfma_f32_16x16x32_bf16: col=lane&15, k=(lane>>4)*8+e.
  short8* Bp = (short8*)Bws;
  const int cb = t & 15, kg = t >> 4;
#pragma unroll
  for (int s = 0; s < 2; ++s) {
#pragma unroll
    for (int nt = 0; nt < 4; ++nt) {
      const int c2 = cb + 16 * nt;
      const int pc = (c2 < 32) ? (2 * c2) : (2 * (c2 - 32) + 1);  // RoPE perm
      short8 hf;
#pragma unroll
      for (int e = 0; e < 8; ++e) {
        const int k = s * 32 + kg * 8 + e;
        hf[e] = (short)f2bf_bits(Ml[k][pc]);
      }
      Bp[(s * 4 + nt) * 64 + t] = hf;
    }
  }
}

__global__ void rope_mfma(
    const float* __restrict__ x,
    const float* __restrict__ inv_freq,
    const short* __restrict__ Bws,
    float* __restrict__ out) {
  const int lane = threadIdx.x & 63;
  const int wid = threadIdx.x >> 6;
  const int cb = lane & 15;   // A row within tile / D col within 16-block
  const int kg = lane >> 4;   // k-group

  const int tile = (int)blockIdx.x * 4 + wid;   // token index
  const size_t rb = (size_t)tile * 16;          // first head-row

  __shared__ alignas(16) float stage[4][16 * 64];
  float* st = stage[wid];

  // --- Fully-contiguous x load: 4 instrs x 1 KB (lane i -> bytes 16i). ---
  const f32x4* xbase = (const f32x4*)(x + rb * 64);  // 4 KB tile
  f32x4 v0 = xbase[lane];
  f32x4 v1 = xbase[64 + lane];
  f32x4 v2 = xbase[128 + lane];
  f32x4 v3 = xbase[192 + lane];

  // B fragments (8 KB table, L2-hot), issued in the same load shadow.
  const short8* Bp = (const short8*)Bws;
  short8 bh[8];
#pragma unroll
  for (int i = 0; i < 8; ++i) bh[i] = Bp[i * 64 + lane];

  // sincos overlaps the loads; one position per tile.
  const int pos = tile & 8191;
  float sv0, cv0, sv1, cv1;
  __sincosf((float)pos * inv_freq[cb], &sv0, &cv0);
  __sincosf((float)pos * inv_freq[cb + 16], &sv1, &cv1);

  // --- Stage x into LDS, XOR-swizzled 16B chunks: (row, chunk c) lives at
  //     float offset row*64 + ((c ^ row)&15)*4. Conflict-spread writes. ---
  {
    const int r0 = lane >> 4;       // row sub-index 0..3
    const int c16 = lane & 15;      // source chunk
    f32x4 vv[4] = {v0, v1, v2, v3};
#pragma unroll
    for (int j = 0; j < 4; ++j) {
      const int row = j * 4 + r0;
      *(f32x4*)&st[row * 64 + (((c16 ^ row) & 15) << 2)] = vv[j];
    }
  }

  // --- Read A-fragments: lane's row = cb, cols [s*32+kg*8, +8). ---
  float af[2][8];
#pragma unroll
  for (int s = 0; s < 2; ++s) {
#pragma unroll
    for (int t2 = 0; t2 < 2; ++t2) {
      const int ch = s * 8 + kg * 2 + t2;   // original 16B chunk index
      f32x4 q = *(const f32x4*)&st[cb * 64 + (((ch ^ cb) & 15) << 2)];
      af[s][t2 * 4 + 0] = q.x;
      af[s][t2 * 4 + 1] = q.y;
      af[s][t2 * 4 + 2] = q.z;
      af[s][t2 * 4 + 3] = q.w;
    }
  }

  // A hi/lo bf16 split (2-term, absmax ~0.031 vs 0.118 threshold).
  short8 ah[2], al[2];
#pragma unroll
  for (int s = 0; s < 2; ++s) {
#pragma unroll
    for (int e = 0; e < 8; ++e) {
      float f = af[s][e];
      __hip_bfloat16 h = __float2bfloat16(f);
      ah[s][e] = (short)__bfloat16_as_ushort(h);
      al[s][e] = (short)f2bf_bits(f - __bfloat162float(h));
    }
  }

  f32x4 acc[4];
#pragma unroll
  for (int nt = 0; nt < 4; ++nt) acc[nt] = (f32x4){0.f, 0.f, 0.f, 0.f};
#pragma unroll
  for (int s = 0; s < 2; ++s) {
#pragma unroll
    for (int nt = 0; nt < 4; ++nt) {
      acc[nt] = __builtin_amdgcn_mfma_f32_16x16x32_bf16(ah[s], bh[s * 4 + nt], acc[nt], 0, 0, 0);
      acc[nt] = __builtin_amdgcn_mfma_f32_16x16x32_bf16(al[s], bh[s * 4 + nt], acc[nt], 0, 0, 0);
    }
  }

  // --- RoPE combine -> same LDS buffer (WAR safe: per-wave DS is in-order,
  //     and the epilogue writes depend on the A reads through acc). ---
#pragma unroll
  for (int nt = 0; nt < 4; ++nt) {
    const float cvx = (nt & 1) ? cv1 : cv0;
    const float ssv = ((nt & 1) ? sv1 : sv0) * ((nt < 2) ? -1.f : 1.f);
    const int chunk = (cb >> 2) + 4 * nt;
    const int c1i = cb & 3;
#pragma unroll
    for (int r = 0; r < 4; ++r) {
      const int lrow = kg * 4 + r;
      float y = acc[nt][r];
      float p = acc[nt ^ 2][r];
      st[lrow * 64 + ((chunk ^ lrow) << 2) + c1i] = fmaf(p, ssv, y * cvx);
    }
  }
  asm volatile("s_waitcnt lgkmcnt(0)");

  // --- 4 contiguous 1 KB nontemporal stores. ---
#pragma unroll
  for (int i = 0; i < 4; ++i) {
    const int g = i * 4 + kg;                      // output row within tile
    const f32x4 v = *(const f32x4*)&st[g * 64 + ((cb ^ g) << 2)];
    __builtin_nontemporal_store(v, (f32x4*)(out + (rb + g) * 64) + cb);
  }
}

extern "C" void kernel_launch(void* const* d_in, const int* in_sizes, int n_in,
                              void* d_out, int out_size, void* d_ws, size_t ws_size,
                              hipStream_t stream) {
  const float* x        = (const float*)d_in[0];
  const float* thetas   = (const float*)d_in[1];
  const float* R        = (const float*)d_in[2];
  const float* inv_freq = (const float*)d_in[3];

  prep_kernel<<<1, 64, 0, stream>>>(thetas, R, (short*)d_ws);
  rope_mfma<<<N_BLOCKS, 256, 0, stream>>>(x, inv_freq, (const short*)d_ws, (float*)d_out);
}